// Round 19
// baseline (157.829 us; speedup 1.0000x reference)
//
#include <hip/hip_runtime.h>
#include <hip/hip_bf16.h>
#include <stdint.h>

typedef __attribute__((ext_vector_type(8))) short bf16x8;
typedef __attribute__((ext_vector_type(4))) float f32x4;

#define CC 256
#define HWP 65536

__device__ __forceinline__ unsigned short f2bf(float f) {
    union { float f; unsigned int u; } v; v.f = f;
    unsigned int u = v.u;
    return (unsigned short)((u + 0x7fffu + ((u >> 16) & 1u)) >> 16);
}
// packed pair conversion (fuses to v_cvt_pk_bf16_f32), RNE like f2bf
__device__ __forceinline__ unsigned int pk2(float lo, float hi) {
    union { __hip_bfloat16 b; unsigned short s; } ul, uh;
    ul.b = __float2bfloat16(lo);
    uh.b = __float2bfloat16(hi);
    return (unsigned)ul.s | ((unsigned)uh.s << 16);
}
__device__ __forceinline__ float sigm_relu(float xn) {
    float xr = fmaxf(xn, 0.f);
    float e = __expf(-xr);
    return __builtin_amdgcn_rcpf(1.f + e);
}

// ---- k1: 512 blocks x 512 thr, 256 px/block, float4 loads + LDS reduce ----
__global__ __launch_bounds__(512, 8) void k1_part(const float* __restrict__ x,
                                                  float* __restrict__ part) {
    __shared__ float red[8][520];
    const int t = threadIdx.x, bid = blockIdx.x;
    const int c4 = (t & 63) * 4, po = t >> 6;     // po 0..7
    const float* xp = x + ((size_t)(bid * 256 + po)) * CC + c4;
    f32x4 s = {0.f, 0.f, 0.f, 0.f}, q = {0.f, 0.f, 0.f, 0.f};
    #pragma unroll 8
    for (int p = 0; p < 32; ++p) {
        f32x4 v = *(const f32x4*)(xp + (size_t)p * 8 * CC);
        s += v; q += v * v;
    }
    *(f32x4*)&red[po][c4] = s;
    *(f32x4*)&red[po][256 + c4] = q;
    __syncthreads();
    float r = 0.f;
    #pragma unroll
    for (int po2 = 0; po2 < 8; ++po2) r += red[po2][t];
    part[bid * 512 + t] = r;
}

// ---- k2: fused two-stage reduce (last-block-done). 32 blocks. ----
__global__ __launch_bounds__(256) void k2_fused(const float* __restrict__ part,
                                                float* __restrict__ p2,
                                                float* __restrict__ mg,
                                                float* __restrict__ ig,
                                                unsigned int* __restrict__ cnt) {
    __shared__ unsigned int done_s;
    const int t = threadIdx.x, r = blockIdx.x;
    float s = 0.f, q = 0.f;
    #pragma unroll
    for (int i = 0; i < 16; ++i) {
        s += part[(size_t)(r * 16 + i) * 512 + t];
        q += part[(size_t)(r * 16 + i) * 512 + 256 + t];
    }
    p2[r * 512 + t] = s;
    p2[r * 512 + 256 + t] = q;
    __threadfence();
    __syncthreads();
    if (t == 0) done_s = atomicAdd(cnt, 1u);
    __syncthreads();
    if (done_s == 31) {      // last block finalizes (p2 is L2-hot)
        __threadfence();
        float s2 = 0.f, q2 = 0.f;
        #pragma unroll
        for (int r2 = 0; r2 < 32; ++r2) {
            s2 += p2[r2 * 512 + t];
            q2 += p2[r2 * 512 + 256 + t];
        }
        float mean = s2 * (1.f / 131072.f);
        float var  = q2 * (1.f / 131072.f) - mean * mean;
        mg[t] = mean;
        ig[t] = rsqrtf(var + 1e-5f);
    }
}

// ---- k3: Gram via MFMA, 256 blocks x 256 px (4 sub-tiles), K split over wave pairs ----
__global__ __launch_bounds__(512) void k3_gram(const float* __restrict__ x,
                                               const float* __restrict__ wd,
                                               const float* __restrict__ mg,
                                               const float* __restrict__ ig,
                                               float* __restrict__ gpart) {
    __shared__ uint4 apack[2048];        // [kb 0..31][n^kb 0..63], 32KB
    __shared__ float y_s[2][16][68];     // [k-half][o][px]
    const int t = threadIdx.x;
    const int w = t >> 6, lm = t & 15, lk = (t >> 4) & 3;
    const int h = w & 1, ntile = w >> 1;     // k-half, px-16-tile
    uint4 wfrag[4];
    #pragma unroll
    for (int kt = 0; kt < 4; ++kt) {
        const int kbr = h * 16 + kt * 4 + lk;
        f32x4 wa = *(const f32x4*)(wd + lm * 256 + kbr * 8);
        f32x4 wb = *(const f32x4*)(wd + lm * 256 + kbr * 8 + 4);
        wfrag[kt] = (uint4){pk2(wa[0], wa[1]), pk2(wa[2], wa[3]),
                            pk2(wb[0], wb[1]), pk2(wb[2], wb[3])};
    }
    const int kb = t & 31, c0 = kb * 8, nb = t >> 5;   // nb 0..15
    f32x4 m0 = *(const f32x4*)(mg + c0), m1 = *(const f32x4*)(mg + c0 + 4);
    f32x4 i0 = *(const f32x4*)(ig + c0), i1 = *(const f32x4*)(ig + c0 + 4);
    const float mm[8] = {m0[0],m0[1],m0[2],m0[3],m1[0],m1[1],m1[2],m1[3]};
    const float ii[8] = {i0[0],i0[1],i0[2],i0[3],i1[0],i1[1],i1[2],i1[3]};
    const int o1 = t >> 4, o2 = t & 15;   // gram pair (t < 256)
    float g = 0.f;
    for (int st = 0; st < 4; ++st) {
        const float* xb = x + ((size_t)(blockIdx.x * 256 + st * 64 + nb)) * CC + c0;
        #pragma unroll
        for (int rep = 0; rep < 4; ++rep) {
            int n = rep * 16 + nb;
            const float* xp = xb + (size_t)rep * 16 * CC;
            f32x4 v0 = *(const f32x4*)xp;
            f32x4 v1 = *(const f32x4*)(xp + 4);
            float vv[8] = {v0[0],v0[1],v0[2],v0[3],v1[0],v1[1],v1[2],v1[3]};
            unsigned aw[4];
            #pragma unroll
            for (int hh = 0; hh < 4; ++hh) {
                float a0 = sigm_relu((vv[2*hh]   - mm[2*hh])   * ii[2*hh]);
                float a1 = sigm_relu((vv[2*hh+1] - mm[2*hh+1]) * ii[2*hh+1]);
                aw[hh] = pk2(a0, a1);
            }
            apack[kb * 64 + (n ^ kb)] = (uint4){aw[0], aw[1], aw[2], aw[3]};
        }
        __syncthreads();
        f32x4 accY = {0.f, 0.f, 0.f, 0.f};
        #pragma unroll
        for (int kt = 0; kt < 4; ++kt) {
            const int kbr = h * 16 + kt * 4 + lk;
            uint4 u = apack[kbr * 64 + ((ntile * 16 + lm) ^ kbr)];
            accY = __builtin_amdgcn_mfma_f32_16x16x32_bf16(*(bf16x8*)&wfrag[kt], *(bf16x8*)&u, accY, 0, 0, 0);
        }
        #pragma unroll
        for (int i = 0; i < 4; ++i) y_s[h][lk * 4 + i][ntile * 16 + lm] = accY[i];
        __syncthreads();
        if (t < 256) {
            #pragma unroll
            for (int p4 = 0; p4 < 16; ++p4) {
                f32x4 a0 = *(const f32x4*)&y_s[0][o1][p4 * 4];
                f32x4 a1 = *(const f32x4*)&y_s[1][o1][p4 * 4];
                f32x4 b0 = *(const f32x4*)&y_s[0][o2][p4 * 4];
                f32x4 b1 = *(const f32x4*)&y_s[1][o2][p4 * 4];
                f32x4 ya = a0 + a1, yb = b0 + b1;
                g += ya[0]*yb[0] + ya[1]*yb[1] + ya[2]*yb[2] + ya[3]*yb[3];
            }
        }
        __syncthreads();
    }
    if (t < 256) gpart[blockIdx.x * 256 + t] = g;
}

// ---- k45: G-reduce + R = G@wd (LDS) + Wcb build, 16 blocks ----
__global__ __launch_bounds__(256) void k45_wcb(const float* __restrict__ gpart,
                                               const float* __restrict__ wd,
                                               const float* __restrict__ wf,
                                               const float* __restrict__ wu,
                                               unsigned short* __restrict__ wcb) {
    __shared__ float G_s[256];
    __shared__ float R_s[16][256];
    __shared__ float M_s[16][17];
    const int t = threadIdx.x;
    float g = 0.f;
    #pragma unroll 8
    for (int i = 0; i < 256; ++i) g += gpart[i * 256 + t];
    G_s[t] = g;
    __syncthreads();
    #pragma unroll
    for (int o = 0; o < 16; ++o) {
        float r = 0.f;
        #pragma unroll
        for (int o2 = 0; o2 < 16; ++o2) r += G_s[o * 16 + o2] * wd[o2 * 256 + t];
        R_s[o][t] = r;
    }
    const int lr = t >> 4, j = t & 15;
    const int r = blockIdx.x * 16 + lr;
    const float* wfr = wf + (size_t)r * 512;
    float m = 0.f;
    for (int c = 0; c < 256; ++c) m += wfr[256 + c] * wu[c * 16 + j];
    M_s[lr][j] = m;
    __syncthreads();
    float Ml[16];
    #pragma unroll
    for (int o = 0; o < 16; ++o) Ml[o] = M_s[lr][o];
    unsigned short* wrow = wcb + (size_t)r * 512;
    for (int i = 0; i < 16; ++i) {
        int c = j + 16 * i;
        wrow[c] = f2bf(wfr[c]);
        float kv = 0.f;
        #pragma unroll
        for (int o = 0; o < 16; ++o) kv += Ml[o] * R_s[o][c];
        wrow[256 + c] = f2bf(kv);
    }
}

// ---- k6: R11 proven structure: 2048 one-shot 64-px blocks, 512 thr, 64KB LDS,
//      batched producer loads, bijective XCD swizzle, NT quartet stores ----
__global__ __launch_bounds__(512, 4) void k6_main(const float* __restrict__ x,
                                                  const unsigned short* __restrict__ wcb,
                                                  const float* __restrict__ mg,
                                                  const float* __restrict__ ig,
                                                  float* __restrict__ out) {
    __shared__ uint4 zpack[4096];   // [kb 0..63][(px^kb)&63] bf16 octets, 64KB
    const int t = threadIdx.x;
    // bijective XCD swizzle: 2048 = 8 XCDs x 256 tiles
    const int tile = (blockIdx.x & 7) * 256 + (blockIdx.x >> 3);
    const int b = tile >> 10;
    const int pw = (tile & 1023) * 64;
    // producer mapping: kb -> channel octet, nb -> px slot (0..15)
    const int kb = t & 31, c0 = kb * 8, nb = t >> 5;
    f32x4 m0 = *(const f32x4*)(mg + c0), m1 = *(const f32x4*)(mg + c0 + 4);
    f32x4 i0 = *(const f32x4*)(ig + c0), i1 = *(const f32x4*)(ig + c0 + 4);
    const float mm[8] = {m0[0],m0[1],m0[2],m0[3],m1[0],m1[1],m1[2],m1[3]};
    const float ii[8] = {i0[0],i0[1],i0[2],i0[3],i1[0],i1[1],i1[2],i1[3]};
    const float* xb = x + ((size_t)(b * HWP + pw + nb)) * CC + c0;
    // batched loads: all 8 f32x4 issued before any conversion
    f32x4 v[8];
    #pragma unroll
    for (int rep = 0; rep < 4; ++rep) {
        v[2 * rep]     = *(const f32x4*)(xb + (size_t)rep * 16 * CC);
        v[2 * rep + 1] = *(const f32x4*)(xb + (size_t)rep * 16 * CC + 4);
    }
    #pragma unroll
    for (int rep = 0; rep < 4; ++rep) {
        const int px = rep * 16 + nb;
        f32x4 v0 = v[2 * rep], v1 = v[2 * rep + 1];
        float vv[8] = {v0[0],v0[1],v0[2],v0[3],v1[0],v1[1],v1[2],v1[3]};
        unsigned xw[4], aw[4];
        #pragma unroll
        for (int hh = 0; hh < 4; ++hh) {
            float xn0 = (vv[2*hh]   - mm[2*hh])   * ii[2*hh];
            float xn1 = (vv[2*hh+1] - mm[2*hh+1]) * ii[2*hh+1];
            xw[hh] = pk2(xn0, xn1);
            aw[hh] = pk2(sigm_relu(xn0), sigm_relu(xn1));
        }
        zpack[kb * 64 + ((px ^ kb) & 63)] = (uint4){xw[0], xw[1], xw[2], xw[3]};
        zpack[(kb + 32) * 64 + ((px ^ (kb + 32)) & 63)] = (uint4){aw[0], aw[1], aw[2], aw[3]};
    }
    __syncthreads();
    // consumer: wave w -> ch rows w*32..+32, px 0..63
    const int w = t >> 6, lm = t & 15, lk = (t >> 4) & 3;
    const unsigned short* wrow = wcb + (size_t)(w * 32 + lm) * 512 + lk * 8;
    f32x4 acc[4][2];
    #pragma unroll
    for (int mt = 0; mt < 4; ++mt)
        #pragma unroll
        for (int nt = 0; nt < 2; ++nt) acc[mt][nt] = (f32x4){0.f, 0.f, 0.f, 0.f};
    #pragma unroll 4
    for (int kt = 0; kt < 16; ++kt) {
        const int kbr = kt * 4 + lk;
        bf16x8 zfr[4], wfr[2];
        #pragma unroll
        for (int mt = 0; mt < 4; ++mt) {
            uint4 u = zpack[kbr * 64 + (((mt * 16 + lm) ^ kbr) & 63)];
            zfr[mt] = *(bf16x8*)&u;
        }
        #pragma unroll
        for (int nt = 0; nt < 2; ++nt)
            wfr[nt] = *(const bf16x8*)(wrow + (size_t)nt * 16 * 512 + kt * 32);
        #pragma unroll
        for (int mt = 0; mt < 4; ++mt)
            #pragma unroll
            for (int nt = 0; nt < 2; ++nt)
                acc[mt][nt] = __builtin_amdgcn_mfma_f32_16x16x32_bf16(zfr[mt], wfr[nt], acc[mt][nt], 0, 0, 0);
    }
    // stores: per row 256 B contiguous via mt quartet
    #pragma unroll
    for (int nt = 0; nt < 2; ++nt) {
        float* ob = out + ((size_t)(b * 256 + w * 32 + nt * 16 + lm)) * HWP + pw + lk * 4;
        #pragma unroll
        for (int mt = 0; mt < 4; ++mt)
            __builtin_nontemporal_store(acc[mt][nt], (f32x4*)(ob + mt * 16));
    }
}

extern "C" void kernel_launch(void* const* d_in, const int* in_sizes, int n_in,
                              void* d_out, int out_size, void* d_ws, size_t ws_size,
                              hipStream_t stream) {
    const float* x  = (const float*)d_in[0];
    const float* wd = (const float*)d_in[1];
    const float* wu = (const float*)d_in[2];
    const float* wf = (const float*)d_in[3];
    float* out = (float*)d_out;
    char* ws = (char*)d_ws;
    unsigned short* wcb = (unsigned short*)ws;               // 256 KiB
    float* part  = (float*)(ws + 262144);                    // 1 MiB
    float* p2    = (float*)(ws + 1310720);                   // 64 KiB
    float* mg    = (float*)(ws + 1376256);                   // 1 KiB
    float* ig    = (float*)(ws + 1377280);                   // 1 KiB
    float* gpart = (float*)(ws + 1378304);                   // 256 KiB
    unsigned int* cnt = (unsigned int*)(ws + 1640448);       // 4 B

    hipMemsetAsync(cnt, 0, 4, stream);
    k1_part <<<dim3(512),  dim3(512), 0, stream>>>(x, part);
    k2_fused<<<dim3(32),   dim3(256), 0, stream>>>(part, p2, mg, ig, cnt);
    k3_gram <<<dim3(256),  dim3(512), 0, stream>>>(x, wd, mg, ig, gpart);
    k45_wcb <<<dim3(16),   dim3(256), 0, stream>>>(gpart, wd, wf, wu, wcb);
    k6_main <<<dim3(2048), dim3(512), 0, stream>>>(x, wcb, mg, ig, out);
}

// Round 20
// 150.710 us; speedup vs baseline: 1.0472x; 1.0472x over previous
//
#include <hip/hip_runtime.h>
#include <hip/hip_bf16.h>
#include <stdint.h>

typedef __attribute__((ext_vector_type(8))) short bf16x8;
typedef __attribute__((ext_vector_type(4))) float f32x4;

#define CC 256
#define HWP 65536

__device__ __forceinline__ unsigned short f2bf(float f) {
    union { float f; unsigned int u; } v; v.f = f;
    unsigned int u = v.u;
    return (unsigned short)((u + 0x7fffu + ((u >> 16) & 1u)) >> 16);
}
// packed pair conversion (fuses to v_cvt_pk_bf16_f32), RNE like f2bf
__device__ __forceinline__ unsigned int pk2(float lo, float hi) {
    union { __hip_bfloat16 b; unsigned short s; } ul, uh;
    ul.b = __float2bfloat16(lo);
    uh.b = __float2bfloat16(hi);
    return (unsigned)ul.s | ((unsigned)uh.s << 16);
}
__device__ __forceinline__ float sigm_relu(float xn) {
    float xr = fmaxf(xn, 0.f);
    float e = __expf(-xr);
    return __builtin_amdgcn_rcpf(1.f + e);
}

// ---- k1: 512 blocks x 512 thr, 256 px/block, float4 loads + LDS reduce ----
__global__ __launch_bounds__(512, 8) void k1_part(const float* __restrict__ x,
                                                  float* __restrict__ part) {
    __shared__ float red[8][520];
    const int t = threadIdx.x, bid = blockIdx.x;
    const int c4 = (t & 63) * 4, po = t >> 6;     // po 0..7
    const float* xp = x + ((size_t)(bid * 256 + po)) * CC + c4;
    f32x4 s = {0.f, 0.f, 0.f, 0.f}, q = {0.f, 0.f, 0.f, 0.f};
    #pragma unroll 8
    for (int p = 0; p < 32; ++p) {
        f32x4 v = *(const f32x4*)(xp + (size_t)p * 8 * CC);
        s += v; q += v * v;
    }
    *(f32x4*)&red[po][c4] = s;
    *(f32x4*)&red[po][256 + c4] = q;
    __syncthreads();
    float r = 0.f;
    #pragma unroll
    for (int po2 = 0; po2 < 8; ++po2) r += red[po2][t];
    part[bid * 512 + t] = r;
}

// ---- k2a: reduce 512 partial rows -> 32 rows ----
__global__ __launch_bounds__(256) void k2a_red(const float* __restrict__ part,
                                               float* __restrict__ p2) {
    int t = threadIdx.x, r = blockIdx.x;
    float s = 0.f, q = 0.f;
    #pragma unroll
    for (int i = 0; i < 16; ++i) {
        s += part[(size_t)(r * 16 + i) * 512 + t];
        q += part[(size_t)(r * 16 + i) * 512 + 256 + t];
    }
    p2[r * 512 + t] = s;
    p2[r * 512 + 256 + t] = q;
}

// ---- k2b: finalize mean / inv-std ----
__global__ __launch_bounds__(256) void k2b_stats(const float* __restrict__ p2,
                                                 float* __restrict__ mg,
                                                 float* __restrict__ ig) {
    int c = threadIdx.x;
    float s = 0.f, q = 0.f;
    #pragma unroll
    for (int r = 0; r < 32; ++r) { s += p2[r * 512 + c]; q += p2[r * 512 + 256 + c]; }
    float mean = s * (1.f / 131072.f);
    float var  = q * (1.f / 131072.f) - mean * mean;
    mg[c] = mean;
    ig[c] = rsqrtf(var + 1e-5f);
}

// ---- k3: Gram via MFMA, 256 blocks x 256 px (4 sub-tiles), K split over wave pairs ----
__global__ __launch_bounds__(512) void k3_gram(const float* __restrict__ x,
                                               const float* __restrict__ wd,
                                               const float* __restrict__ mg,
                                               const float* __restrict__ ig,
                                               float* __restrict__ gpart) {
    __shared__ uint4 apack[2048];        // [kb 0..31][n^kb 0..63], 32KB
    __shared__ float y_s[2][16][68];     // [k-half][o][px]
    const int t = threadIdx.x;
    const int w = t >> 6, lm = t & 15, lk = (t >> 4) & 3;
    const int h = w & 1, ntile = w >> 1;     // k-half, px-16-tile
    uint4 wfrag[4];
    #pragma unroll
    for (int kt = 0; kt < 4; ++kt) {
        const int kbr = h * 16 + kt * 4 + lk;
        f32x4 wa = *(const f32x4*)(wd + lm * 256 + kbr * 8);
        f32x4 wb = *(const f32x4*)(wd + lm * 256 + kbr * 8 + 4);
        wfrag[kt] = (uint4){pk2(wa[0], wa[1]), pk2(wa[2], wa[3]),
                            pk2(wb[0], wb[1]), pk2(wb[2], wb[3])};
    }
    const int kb = t & 31, c0 = kb * 8, nb = t >> 5;   // nb 0..15
    f32x4 m0 = *(const f32x4*)(mg + c0), m1 = *(const f32x4*)(mg + c0 + 4);
    f32x4 i0 = *(const f32x4*)(ig + c0), i1 = *(const f32x4*)(ig + c0 + 4);
    const float mm[8] = {m0[0],m0[1],m0[2],m0[3],m1[0],m1[1],m1[2],m1[3]};
    const float ii[8] = {i0[0],i0[1],i0[2],i0[3],i1[0],i1[1],i1[2],i1[3]};
    const int o1 = t >> 4, o2 = t & 15;   // gram pair (t < 256)
    float g = 0.f;
    for (int st = 0; st < 4; ++st) {
        const float* xb = x + ((size_t)(blockIdx.x * 256 + st * 64 + nb)) * CC + c0;
        #pragma unroll
        for (int rep = 0; rep < 4; ++rep) {
            int n = rep * 16 + nb;
            const float* xp = xb + (size_t)rep * 16 * CC;
            f32x4 v0 = *(const f32x4*)xp;
            f32x4 v1 = *(const f32x4*)(xp + 4);
            float vv[8] = {v0[0],v0[1],v0[2],v0[3],v1[0],v1[1],v1[2],v1[3]};
            unsigned aw[4];
            #pragma unroll
            for (int hh = 0; hh < 4; ++hh) {
                float a0 = sigm_relu((vv[2*hh]   - mm[2*hh])   * ii[2*hh]);
                float a1 = sigm_relu((vv[2*hh+1] - mm[2*hh+1]) * ii[2*hh+1]);
                aw[hh] = pk2(a0, a1);
            }
            apack[kb * 64 + (n ^ kb)] = (uint4){aw[0], aw[1], aw[2], aw[3]};
        }
        __syncthreads();
        f32x4 accY = {0.f, 0.f, 0.f, 0.f};
        #pragma unroll
        for (int kt = 0; kt < 4; ++kt) {
            const int kbr = h * 16 + kt * 4 + lk;
            uint4 u = apack[kbr * 64 + ((ntile * 16 + lm) ^ kbr)];
            accY = __builtin_amdgcn_mfma_f32_16x16x32_bf16(*(bf16x8*)&wfrag[kt], *(bf16x8*)&u, accY, 0, 0, 0);
        }
        #pragma unroll
        for (int i = 0; i < 4; ++i) y_s[h][lk * 4 + i][ntile * 16 + lm] = accY[i];
        __syncthreads();
        if (t < 256) {
            #pragma unroll
            for (int p4 = 0; p4 < 16; ++p4) {
                f32x4 a0 = *(const f32x4*)&y_s[0][o1][p4 * 4];
                f32x4 a1 = *(const f32x4*)&y_s[1][o1][p4 * 4];
                f32x4 b0 = *(const f32x4*)&y_s[0][o2][p4 * 4];
                f32x4 b1 = *(const f32x4*)&y_s[1][o2][p4 * 4];
                f32x4 ya = a0 + a1, yb = b0 + b1;
                g += ya[0]*yb[0] + ya[1]*yb[1] + ya[2]*yb[2] + ya[3]*yb[3];
            }
        }
        __syncthreads();
    }
    if (t < 256) gpart[blockIdx.x * 256 + t] = g;
}

// ---- k45: G-reduce + R = G@wd (LDS) + Wcb build, 16 blocks ----
__global__ __launch_bounds__(256) void k45_wcb(const float* __restrict__ gpart,
                                               const float* __restrict__ wd,
                                               const float* __restrict__ wf,
                                               const float* __restrict__ wu,
                                               unsigned short* __restrict__ wcb) {
    __shared__ float G_s[256];
    __shared__ float R_s[16][256];
    __shared__ float M_s[16][17];
    const int t = threadIdx.x;
    float g = 0.f;
    #pragma unroll 8
    for (int i = 0; i < 256; ++i) g += gpart[i * 256 + t];
    G_s[t] = g;
    __syncthreads();
    #pragma unroll
    for (int o = 0; o < 16; ++o) {
        float r = 0.f;
        #pragma unroll
        for (int o2 = 0; o2 < 16; ++o2) r += G_s[o * 16 + o2] * wd[o2 * 256 + t];
        R_s[o][t] = r;
    }
    const int lr = t >> 4, j = t & 15;
    const int r = blockIdx.x * 16 + lr;
    const float* wfr = wf + (size_t)r * 512;
    float m = 0.f;
    for (int c = 0; c < 256; ++c) m += wfr[256 + c] * wu[c * 16 + j];
    M_s[lr][j] = m;
    __syncthreads();
    float Ml[16];
    #pragma unroll
    for (int o = 0; o < 16; ++o) Ml[o] = M_s[lr][o];
    unsigned short* wrow = wcb + (size_t)r * 512;
    for (int i = 0; i < 16; ++i) {
        int c = j + 16 * i;
        wrow[c] = f2bf(wfr[c]);
        float kv = 0.f;
        #pragma unroll
        for (int o = 0; o < 16; ++o) kv += Ml[o] * R_s[o][c];
        wrow[256 + c] = f2bf(kv);
    }
}

// ---- k6: R11/R18 proven structure: 2048 one-shot 64-px blocks, 512 thr,
//      64KB LDS, batched producer loads, bijective XCD swizzle, NT stores ----
__global__ __launch_bounds__(512, 4) void k6_main(const float* __restrict__ x,
                                                  const unsigned short* __restrict__ wcb,
                                                  const float* __restrict__ mg,
                                                  const float* __restrict__ ig,
                                                  float* __restrict__ out) {
    __shared__ uint4 zpack[4096];   // [kb 0..63][(px^kb)&63] bf16 octets, 64KB
    const int t = threadIdx.x;
    // bijective XCD swizzle: 2048 = 8 XCDs x 256 tiles
    const int tile = (blockIdx.x & 7) * 256 + (blockIdx.x >> 3);
    const int b = tile >> 10;
    const int pw = (tile & 1023) * 64;
    // producer mapping: kb -> channel octet, nb -> px slot (0..15)
    const int kb = t & 31, c0 = kb * 8, nb = t >> 5;
    f32x4 m0 = *(const f32x4*)(mg + c0), m1 = *(const f32x4*)(mg + c0 + 4);
    f32x4 i0 = *(const f32x4*)(ig + c0), i1 = *(const f32x4*)(ig + c0 + 4);
    const float mm[8] = {m0[0],m0[1],m0[2],m0[3],m1[0],m1[1],m1[2],m1[3]};
    const float ii[8] = {i0[0],i0[1],i0[2],i0[3],i1[0],i1[1],i1[2],i1[3]};
    const float* xb = x + ((size_t)(b * HWP + pw + nb)) * CC + c0;
    // batched loads: all 8 f32x4 issued before any conversion
    f32x4 v[8];
    #pragma unroll
    for (int rep = 0; rep < 4; ++rep) {
        v[2 * rep]     = *(const f32x4*)(xb + (size_t)rep * 16 * CC);
        v[2 * rep + 1] = *(const f32x4*)(xb + (size_t)rep * 16 * CC + 4);
    }
    #pragma unroll
    for (int rep = 0; rep < 4; ++rep) {
        const int px = rep * 16 + nb;
        f32x4 v0 = v[2 * rep], v1 = v[2 * rep + 1];
        float vv[8] = {v0[0],v0[1],v0[2],v0[3],v1[0],v1[1],v1[2],v1[3]};
        unsigned xw[4], aw[4];
        #pragma unroll
        for (int hh = 0; hh < 4; ++hh) {
            float xn0 = (vv[2*hh]   - mm[2*hh])   * ii[2*hh];
            float xn1 = (vv[2*hh+1] - mm[2*hh+1]) * ii[2*hh+1];
            xw[hh] = pk2(xn0, xn1);
            aw[hh] = pk2(sigm_relu(xn0), sigm_relu(xn1));
        }
        zpack[kb * 64 + ((px ^ kb) & 63)] = (uint4){xw[0], xw[1], xw[2], xw[3]};
        zpack[(kb + 32) * 64 + ((px ^ (kb + 32)) & 63)] = (uint4){aw[0], aw[1], aw[2], aw[3]};
    }
    __syncthreads();
    // consumer: wave w -> ch rows w*32..+32, px 0..63
    const int w = t >> 6, lm = t & 15, lk = (t >> 4) & 3;
    const unsigned short* wrow = wcb + (size_t)(w * 32 + lm) * 512 + lk * 8;
    f32x4 acc[4][2];
    #pragma unroll
    for (int mt = 0; mt < 4; ++mt)
        #pragma unroll
        for (int nt = 0; nt < 2; ++nt) acc[mt][nt] = (f32x4){0.f, 0.f, 0.f, 0.f};
    #pragma unroll 4
    for (int kt = 0; kt < 16; ++kt) {
        const int kbr = kt * 4 + lk;
        bf16x8 zfr[4], wfr[2];
        #pragma unroll
        for (int mt = 0; mt < 4; ++mt) {
            uint4 u = zpack[kbr * 64 + (((mt * 16 + lm) ^ kbr) & 63)];
            zfr[mt] = *(bf16x8*)&u;
        }
        #pragma unroll
        for (int nt = 0; nt < 2; ++nt)
            wfr[nt] = *(const bf16x8*)(wrow + (size_t)nt * 16 * 512 + kt * 32);
        #pragma unroll
        for (int mt = 0; mt < 4; ++mt)
            #pragma unroll
            for (int nt = 0; nt < 2; ++nt)
                acc[mt][nt] = __builtin_amdgcn_mfma_f32_16x16x32_bf16(zfr[mt], wfr[nt], acc[mt][nt], 0, 0, 0);
    }
    // stores: per row 256 B contiguous via mt quartet
    #pragma unroll
    for (int nt = 0; nt < 2; ++nt) {
        float* ob = out + ((size_t)(b * 256 + w * 32 + nt * 16 + lm)) * HWP + pw + lk * 4;
        #pragma unroll
        for (int mt = 0; mt < 4; ++mt)
            __builtin_nontemporal_store(acc[mt][nt], (f32x4*)(ob + mt * 16));
    }
}

extern "C" void kernel_launch(void* const* d_in, const int* in_sizes, int n_in,
                              void* d_out, int out_size, void* d_ws, size_t ws_size,
                              hipStream_t stream) {
    const float* x  = (const float*)d_in[0];
    const float* wd = (const float*)d_in[1];
    const float* wu = (const float*)d_in[2];
    const float* wf = (const float*)d_in[3];
    float* out = (float*)d_out;
    char* ws = (char*)d_ws;
    unsigned short* wcb = (unsigned short*)ws;               // 256 KiB
    float* part  = (float*)(ws + 262144);                    // 1 MiB
    float* p2    = (float*)(ws + 1310720);                   // 64 KiB
    float* mg    = (float*)(ws + 1376256);                   // 1 KiB
    float* ig    = (float*)(ws + 1377280);                   // 1 KiB
    float* gpart = (float*)(ws + 1378304);                   // 256 KiB

    k1_part <<<dim3(512),  dim3(512), 0, stream>>>(x, part);
    k2a_red <<<dim3(32),   dim3(256), 0, stream>>>(part, p2);
    k2b_stats<<<dim3(1),   dim3(256), 0, stream>>>(p2, mg, ig);
    k3_gram <<<dim3(256),  dim3(512), 0, stream>>>(x, wd, mg, ig, gpart);
    k45_wcb <<<dim3(16),   dim3(256), 0, stream>>>(gpart, wd, wf, wu, wcb);
    k6_main <<<dim3(2048), dim3(512), 0, stream>>>(x, wcb, mg, ig, out);
}